// Round 5
// baseline (772.481 us; speedup 1.0000x reference)
//
#include <hip/hip_runtime.h>
#include <hip/hip_bf16.h>

// B=4, N=256, F=64, H=256, A=16, T=3. BN=1024 rows.
// Single persistent kernel (grid=256=CU count, co-resident) with device-scope
// barriers; all GEMMs bf16 MFMA 16x16x32 with split hi/lo activations + dup-K
// weights (X now split too -- R4's residual error source).

typedef unsigned short ushort_t;
typedef short bf8_t __attribute__((ext_vector_type(8)));
typedef float f4_t  __attribute__((ext_vector_type(4)));

#define NBLK 256

// ---- ushort offsets ----
#define UB_NFB    0          // [1024][64]
#define UB_PW1T   65536      // [256][64]
#define UB_PW2T   81920      // [256][512] dup
#define UB_WCATT  212992     // [1280][512] dup  = [W1_i|W1_j|Whh]^T
#define UB_W2HT   868352     // [256][576] dup   (col k=256 = msg_b2 via deg)
#define UB_WIHT   1015808    // [768][512] dup
#define UB_X2     1409024    // [1024][512] hi|lo
#define UB_H2     1933312    // [1024][512] hi|lo
#define UB_EHAT2  2457600    // [1024][576] hi(288)|lo(288)
#define UB_AGG2   3047424    // [1024][512] hi|lo
// ---- float offsets ----
#define F_PREB1   1785856    // 256
#define F_PREB2   1786112    // 256
#define F_BCAT    1786368    // 1280 [msg_b1|0|gru_bhh]
#define F_BIH     1787648    // 768
#define F_ROW1    1788416    // 65536
#define F_ROB1    1853952    // 256
#define F_ROW2    1854208    // 4096
#define F_ROB2    1858304    // 16
#define F_H       1858320    // 262144
#define F_HCAT    2120464    // 1310720 [hi_p|hj|gh]
#define F_GI      3431184    // 786432
#define F_BAR     4217616    // 32 unsigned

// ---- convert index space ----
#define CVa 65536
#define CVb 81920
#define CVc 212992
#define CVd 868352
#define CVe 1015808
#define CVf 1409024
#define CV_TOTAL 1481488     // CVf + 72464 fp32 tail

__device__ __forceinline__ float bf2f(ushort_t u) {
    return __uint_as_float(((unsigned int)u) << 16);
}
__device__ __forceinline__ ushort_t f2b(float v) {
    __hip_bfloat16 b = __float2bfloat16(v);
    return *reinterpret_cast<ushort_t*>(&b);
}
__device__ __forceinline__ float relu(float v) { return v < 0.f ? 0.f : v; }
__device__ __forceinline__ float ld(const void* p, int i, int isf32) {
    return isf32 ? ((const float*)p)[i] : bf2f(((const ushort_t*)p)[i]);
}

// Grid-wide barrier: per-round counter (zeroed by host memset each call).
// Release fence -> device-scope arrive -> spin -> acquire fence.
__device__ __forceinline__ void gridbar(unsigned* bar) {
    __syncthreads();
    if (threadIdx.x == 0) {
        __threadfence();
        atomicAdd(bar, 1u);
        while (__hip_atomic_load(bar, __ATOMIC_RELAXED, __HIP_MEMORY_SCOPE_AGENT) < NBLK)
            __builtin_amdgcn_s_sleep(2);
        __threadfence();
    }
    __syncthreads();
}

// One 128x128 output tile of C[M,N] = A[M,K] @ Bt[N,K]^T (+bias)(+relu).
// 4 waves of 64x64. K%32==0. C fp32 optional; Cb bf16 optional (stride cbld,
// lo-residual at +cblo if cblo!=0).
__device__ void mgemm_tile(const ushort_t* __restrict__ A, const ushort_t* __restrict__ Bt,
                           const float* __restrict__ bias, float* __restrict__ C,
                           ushort_t* __restrict__ Cb, int cbld, int cblo,
                           int K, int N, int dorelu, int tile, int ntn,
                           ushort_t* As, ushort_t* Bs)
{
    const int t = threadIdx.x;
    const int wave = t >> 6, lane = t & 63;
    const int ln = lane & 15, quad = lane >> 4;
    const int bm = (tile / ntn) * 128, bn = (tile % ntn) * 128;
    const int wm = (wave >> 1) * 64, wn = (wave & 1) * 64;
    const int srow = t >> 2, skc = (t & 3) << 3;

    f4_t acc[4][4] = {};

    for (int k0 = 0; k0 < K; k0 += 32) {
        __syncthreads();
#pragma unroll
        for (int r = 0; r < 2; ++r) {
            int row = srow + r * 64;
            *(bf8_t*)(&As[row * 32 + skc]) = *(const bf8_t*)(&A[(bm + row) * K + k0 + skc]);
            *(bf8_t*)(&Bs[row * 32 + skc]) = *(const bf8_t*)(&Bt[(bn + row) * K + k0 + skc]);
        }
        __syncthreads();
        bf8_t af[4], bfr[4];
#pragma unroll
        for (int i = 0; i < 4; ++i) {
            af[i]  = *(const bf8_t*)(&As[(wm + i * 16 + ln) * 32 + quad * 8]);
            bfr[i] = *(const bf8_t*)(&Bs[(wn + i * 16 + ln) * 32 + quad * 8]);
        }
#pragma unroll
        for (int mi = 0; mi < 4; ++mi)
#pragma unroll
            for (int ni = 0; ni < 4; ++ni)
                acc[mi][ni] = __builtin_amdgcn_mfma_f32_16x16x32_bf16(
                    af[mi], bfr[ni], acc[mi][ni], 0, 0, 0);
    }

#pragma unroll
    for (int mi = 0; mi < 4; ++mi) {
#pragma unroll
        for (int ni = 0; ni < 4; ++ni) {
            int col = bn + wn + ni * 16 + ln;
            float bb = bias ? bias[col] : 0.f;
#pragma unroll
            for (int r = 0; r < 4; ++r) {
                int row = bm + wm + mi * 16 + quad * 4 + r;
                float v = acc[mi][ni][r] + bb;
                if (dorelu) v = relu(v);
                if (C) C[row * N + col] = v;
                if (Cb) {
                    ushort_t hi = f2b(v);
                    Cb[row * cbld + col] = hi;
                    if (cblo) Cb[row * cbld + cblo + col] = f2b(v - bf2f(hi));
                }
            }
        }
    }
}

__global__ __launch_bounds__(256) void mono_kernel(
    const void* nf, const void* p_adj,
    const void* preW1, const void* preb1, const void* preW2, const void* preb2,
    const void* msgW1, const void* msgb1, const void* msgW2, const void* msgb2,
    const void* gruWih, const void* gruWhh, const void* grubih, const void* grubhh,
    const void* roW1, const void* rob1, const void* roW2, const void* rob2,
    float* __restrict__ w, void* __restrict__ out)
{
    __shared__ ushort_t smem[8192];   // 16 KB, overlaid per stage
    ushort_t* As = smem;
    ushort_t* Bs = smem + 4096;
    const int bid = blockIdx.x;
    const int t = threadIdx.x;
    ushort_t* wb = (ushort_t*)w;
    unsigned* bar = (unsigned*)(w + F_BAR);
    int br = 0;
    const int* adj = (const int*)p_adj;

    // ---- S0: dtype detect (block-local, every block identical) ----
    int* cnt = (int*)smem;
    if (t == 0) *cnt = 0;
    __syncthreads();
    {
        const ushort_t* nf16 = (const ushort_t*)nf;
        int bad = 0;
        for (int i = 0; i < 8; ++i) {
            ushort_t u = nf16[(t * 8 + i) * 2];
            int ex = (u >> 7) & 0xFF;
            if ((u & 0x7fff) != 0 && (ex < 100 || ex > 140)) bad++;
        }
        atomicAdd(cnt, bad);
    }
    __syncthreads();
    const int f32 = (*cnt > 512) ? 1 : 0;
    __syncthreads();

    // ---- S1: convert / build weights ----
    for (int e = bid * 256 + t; e < CV_TOTAL; e += NBLK * 256) {
        if (e < CVa) {
            wb[UB_NFB + e] = f2b(ld(nf, e, f32));
        } else if (e < CVb) {                       // preW1^T [256][64]
            int i = e - CVa; int n = i >> 6, k = i & 63;
            wb[UB_PW1T + i] = f2b(ld(preW1, k * 256 + n, f32));
        } else if (e < CVc) {                       // preW2^T dup [256][512]
            int i = e - CVb; int n = i >> 9, k = i & 255;
            wb[UB_PW2T + i] = f2b(ld(preW2, k * 256 + n, f32));
        } else if (e < CVd) {                       // Wcat^T dup [1280][512]
            int i = e - CVc; int n = i >> 9, k = i & 255;
            float v;
            if (n < 256)      v = ld(msgW1, k * 256 + n, f32);
            else if (n < 512) v = ld(msgW1, (256 + k) * 256 + (n - 256), f32);
            else              v = ld(gruWhh, k * 768 + (n - 512), f32);
            wb[UB_WCATT + i] = f2b(v);
        } else if (e < CVe) {                       // W2hat^T dup [256][576]
            int i = e - CVd; int n = i / 576, k = i - n * 576, km = k % 288;
            float v;
            if (km < 256)       v = ld(msgW2, km * 256 + n, f32);
            else if (km == 256) v = ld(msgb2, n, f32);
            else                v = 0.f;
            wb[UB_W2HT + i] = f2b(v);
        } else if (e < CVf) {                       // Wih^T dup [768][512]
            int i = e - CVe; int n = i >> 9, k = i & 255;
            wb[UB_WIHT + i] = f2b(ld(gruWih, k * 768 + n, f32));
        } else {                                    // fp32 tail
            int f = e - CVf;
            float v;
            if (f < 256)        v = ld(preb1, f, f32);
            else if (f < 512)   v = ld(preb2, f - 256, f32);
            else if (f < 1792) {
                int c = f - 512;
                if (c < 256)      v = ld(msgb1, c, f32);
                else if (c < 512) v = 0.f;
                else              v = ld(grubhh, c - 512, f32);
            }
            else if (f < 2560)  v = ld(grubih, f - 1792, f32);
            else if (f < 68096) v = ld(roW1, f - 2560, f32);
            else if (f < 68352) v = ld(rob1, f - 68096, f32);
            else if (f < 72448) v = ld(roW2, f - 68352, f32);
            else                v = ld(rob2, f - 72448, f32);
            w[F_PREB1 + f] = v;
        }
    }
    gridbar(&bar[br++]);

    // ---- S2: X = relu(NF@preW1+b1) -> X2 hi|lo ----
    if (bid < 16)
        mgemm_tile(wb + UB_NFB, wb + UB_PW1T, w + F_PREB1, (float*)0,
                   wb + UB_X2, 512, 256, 64, 256, 1, bid, 2, As, Bs);
    gridbar(&bar[br++]);

    // ---- S3: h = X2@preW2dup+b2 -> F_H fp32 + H2 hi|lo ----
    if (bid < 16)
        mgemm_tile(wb + UB_X2, wb + UB_PW2T, w + F_PREB2, w + F_H,
                   wb + UB_H2, 512, 256, 512, 256, 0, bid, 2, As, Bs);
    gridbar(&bar[br++]);

    for (int it = 0; it < 3; ++it) {
        // hcat = h @ [W1_i|W1_j|Whh] + [b1|0|bhh] -> fp32 [1024][1280]
        if (bid < 80)
            mgemm_tile(wb + UB_H2, wb + UB_WCATT, w + F_BCAT, w + F_HCAT,
                       (ushort_t*)0, 0, 0, 512, 1280, 0, bid, 10, As, Bs);
        gridbar(&bar[br++]);

        // msg: Ehat rows (4 per block)
        {
            int* ej = (int*)smem;
            int* ecnt = (int*)smem + 256;
            const int batch = (bid * 4) >> 8;
            const float* hjb = w + F_HCAT + batch * 256 * 1280 + 256;
            for (int rr = 0; rr < 4; ++rr) {
                const int row = bid * 4 + rr;
                __syncthreads();
                if (t == 0) *ecnt = 0;
                __syncthreads();
                if (adj[row * 256 + t]) { int p = atomicAdd(ecnt, 1); ej[p] = t; }
                const float hi = w[F_HCAT + row * 1280 + t];
                __syncthreads();
                const int ne = *ecnt;
                float acc = 0.f;
#pragma unroll 8
                for (int p = 0; p < ne; ++p) {
                    int j = ej[p];
                    acc += relu(hi + hjb[j * 1280 + t]);
                }
                ushort_t h16 = f2b(acc);
                wb[UB_EHAT2 + row * 576 + t] = h16;
                wb[UB_EHAT2 + row * 576 + 288 + t] = f2b(acc - bf2f(h16));
                if (t < 32) {
                    wb[UB_EHAT2 + row * 576 + 256 + t] = f2b(t == 0 ? (float)ne : 0.f);
                    wb[UB_EHAT2 + row * 576 + 544 + t] = 0;
                }
            }
        }
        gridbar(&bar[br++]);

        // agg = Ehat @ W2hat -> AGG2 hi|lo
        if (bid < 16)
            mgemm_tile(wb + UB_EHAT2, wb + UB_W2HT, (const float*)0, (float*)0,
                       wb + UB_AGG2, 512, 256, 576, 256, 0, bid, 2, As, Bs);
        gridbar(&bar[br++]);

        // gi = agg @ Wih + bih -> fp32 [1024][768]
        if (bid < 48)
            mgemm_tile(wb + UB_AGG2, wb + UB_WIHT, w + F_BIH, w + F_GI,
                       (ushort_t*)0, 0, 0, 512, 768, 0, bid, 6, As, Bs);
        gridbar(&bar[br++]);

        // GRU update (4 rows per block)
        for (int rr = 0; rr < 4; ++rr) {
            const int row = bid * 4 + rr;
            const float* gir = w + F_GI + row * 768;
            const float* ghr = w + F_HCAT + row * 1280 + 512;
            float ir = gir[t], iz = gir[256 + t], in = gir[512 + t];
            float hr = ghr[t], hz = ghr[256 + t], hn = ghr[512 + t];
            float r = 1.f / (1.f + __expf(-(ir + hr)));
            float z = 1.f / (1.f + __expf(-(iz + hz)));
            float n = tanhf(in + r * hn);
            float ho = w[F_H + row * 256 + t];
            float hv = (1.f - z) * n + z * ho;
            w[F_H + row * 256 + t] = hv;
            ushort_t hb = f2b(hv);
            wb[UB_H2 + row * 512 + t] = hb;
            wb[UB_H2 + row * 512 + 256 + t] = f2b(hv - bf2f(hb));
        }
        gridbar(&bar[br++]);
    }

    // ---- readout (blocks 0..3) ----
    if (bid < 4) {
        float* gl = (float*)smem;
        float* t1 = gl + 256;
        const float* hb = w + F_H + bid * 256 * 256;
        float s = 0.f;
        for (int n = 0; n < 256; ++n) s += hb[n * 256 + t];
        gl[t] = s;
        __syncthreads();
        float acc = w[F_ROB1 + t];
        for (int k = 0; k < 256; ++k) acc += gl[k] * w[F_ROW1 + k * 256 + t];
        t1[t] = relu(acc);
        __syncthreads();
        if (t < 16) {
            float q = w[F_ROB2 + t];
            for (int k = 0; k < 256; ++k) q += t1[k] * w[F_ROW2 + k * 16 + t];
            if (f32) ((float*)out)[bid * 16 + t] = q;
            else ((__hip_bfloat16*)out)[bid * 16 + t] = __float2bfloat16(q);
        }
    }
}

extern "C" void kernel_launch(void* const* d_in, const int* in_sizes, int n_in,
                              void* d_out, int out_size, void* d_ws, size_t ws_size,
                              hipStream_t stream) {
    float* w = (float*)d_ws;

    static const int dictSz[18]  = {65536,262144,16384,256,65536,256,131072,256,65536,256,
                                    196608,196608,768,768,65536,256,4096,16};
    static const int alphaSz[18] = {262144,196608,196608,768,768,131072,65536,256,256,
                                    65536,16384,65536,256,256,65536,4096,256,16};
    static const int alphaPos[18] = {9,0,10,12,11,13,5,7,6,8,2,1,4,3,14,16,15,17};
    bool dictOK = true, alphaOK = true;
    for (int i = 0; i < 18 && i < n_in; ++i) {
        if (in_sizes[i] != dictSz[i])  dictOK = false;
        if (in_sizes[i] != alphaSz[i]) alphaOK = false;
    }
    const void* P[18];
    for (int l = 0; l < 18; ++l) P[l] = d_in[(!dictOK && alphaOK) ? alphaPos[l] : l];

    hipMemsetAsync((void*)(w + F_BAR), 0, 32 * sizeof(unsigned), stream);
    mono_kernel<<<NBLK, 256, 0, stream>>>(
        P[0], P[1], P[2], P[3], P[4], P[5], P[6], P[7], P[8], P[9],
        P[10], P[11], P[12], P[13], P[14], P[15], P[16], P[17], w, d_out);
}

// Round 7
// 549.662 us; speedup vs baseline: 1.4054x; 1.4054x over previous
//
#include <hip/hip_runtime.h>
#include <hip/hip_bf16.h>

// B=4, N=256, F=64, H=256, A=16, T=3. BN=1024.
// Multi-kernel (regular launches, graph-capture safe). bf16 MFMA 16x16x32,
// BK=64 VGPR-pipelined staging, padded LDS. Split hi/lo activations + dup-K
// weights (~fp32 accuracy). agg+gi fused via Wcomb = W2hat@Wih (K=896).
// 16 launches total: conv, pre1, pre2, 3x(hcat, msg, gi, gru), readout.

typedef unsigned short ushort_t;
typedef short bf8_t __attribute__((ext_vector_type(8)));
typedef float f4_t  __attribute__((ext_vector_type(4)));

#define LDA 72   // LDS row pitch (ushort): 144 B = 9*16 keeps b128 alignment

// ---- ushort offsets ----
#define UB_NFB     0          // [1024][64]
#define UB_PW1T    65536      // [256][64]
#define UB_PW2T    81920      // [256][512] dup
#define UB_WCATT   212992     // [1280][512] dup = [W1_i|W1_j|Whh]^T
#define UB_WCOMBT  868352     // [768][896]: [Wc_hi|Wc_hi|Wc_lo], live k%288<=256,k<864
#define UB_X2      1556480    // [1024][512] hi|lo
#define UB_H2      2080768    // [1024][512] hi|lo
#define UB_EHAT    2605056    // [1024][896]: [hi(288)|lo(288)|hi(288)|0(32)]
// ---- float offsets ----
#define F_PREB1    1761280    // 256
#define F_PREB2    1761536    // 256
#define F_BCAT     1761792    // 1280 [msg_b1|0|gru_bhh]
#define F_BIH      1763072    // 768
#define F_ROW1     1763840    // 65536
#define F_ROB1     1829376    // 256
#define F_ROW2     1829632    // 4096
#define F_ROB2     1833728    // 16
#define F_H        1833744    // 262144
#define F_HCAT     2095888    // 1310720 [hi_p(256)|hj(256)|gh(768)]
#define F_GI       3406608    // 786432
#define F_FLAG     4193040    // 1 int   (~16.8 MB total)

// ---- convert index space ----
#define CVa 65536      // NFB
#define CVb 81920      // PW1T
#define CVc 212992     // PW2T
#define CVd 868352     // WCATT
#define CVe 1556480    // WCOMBT (zero-slots only here)
#define CV_TOTAL 1628944  // CVe + 72464 fp32 tail

__device__ __forceinline__ float bf2f(ushort_t u) {
    return __uint_as_float(((unsigned int)u) << 16);
}
__device__ __forceinline__ ushort_t f2b(float v) {
    __hip_bfloat16 b = __float2bfloat16(v);
    return *reinterpret_cast<ushort_t*>(&b);
}
__device__ __forceinline__ float relu(float v) { return v < 0.f ? 0.f : v; }
__device__ __forceinline__ float ld(const void* p, int i, int isf32) {
    return isf32 ? ((const float*)p)[i] : bf2f(((const ushort_t*)p)[i]);
}

// Convert + detect + Wcomb precompute. Grid 256x256.
__global__ __launch_bounds__(256) void conv_kernel(
    const void* nf,
    const void* preW1, const void* preb1, const void* preW2, const void* preb2,
    const void* msgW1, const void* msgb1, const void* msgW2, const void* msgb2,
    const void* gruWih, const void* gruWhh, const void* grubih, const void* grubhh,
    const void* roW1, const void* rob1, const void* roW2, const void* rob2,
    float* __restrict__ w)
{
    const int bid = blockIdx.x, t = threadIdx.x;
    ushort_t* wb = (ushort_t*)w;

    // block-local dtype detect (identical result in every block)
    __shared__ int cnt;
    if (t == 0) cnt = 0;
    __syncthreads();
    {
        const ushort_t* nf16 = (const ushort_t*)nf;
        int bad = 0;
        for (int i = 0; i < 8; ++i) {
            ushort_t u = nf16[(t * 8 + i) * 2];
            int ex = (u >> 7) & 0xFF;
            if ((u & 0x7fff) != 0 && (ex < 100 || ex > 140)) bad++;
        }
        atomicAdd(&cnt, bad);
    }
    __syncthreads();
    const int f32 = (cnt > 512) ? 1 : 0;
    if (t == 0) ((int*)(w + F_FLAG))[0] = f32;   // same value from all blocks

    for (int e = bid * 256 + t; e < CV_TOTAL; e += 256 * 256) {
        if (e < CVa) {
            wb[UB_NFB + e] = f2b(ld(nf, e, f32));
        } else if (e < CVb) {                       // preW1^T [256][64]
            int i = e - CVa; int n = i >> 6, k = i & 63;
            wb[UB_PW1T + i] = f2b(ld(preW1, k * 256 + n, f32));
        } else if (e < CVc) {                       // preW2^T dup [256][512]
            int i = e - CVb; int n = i >> 9, k = i & 255;
            wb[UB_PW2T + i] = f2b(ld(preW2, k * 256 + n, f32));
        } else if (e < CVd) {                       // Wcat^T dup [1280][512]
            int i = e - CVc; int n = i >> 9, k = i & 255;
            float v;
            if (n < 256)      v = ld(msgW1, k * 256 + n, f32);
            else if (n < 512) v = ld(msgW1, (256 + k) * 256 + (n - 256), f32);
            else              v = ld(gruWhh, k * 768 + (n - 512), f32);
            wb[UB_WCATT + i] = f2b(v);
        } else if (e < CVe) {                       // WCOMBT zero slots only
            int i = e - CVd; int k = i % 896;
            if (k >= 864 || (k % 288) >= 257) wb[UB_WCOMBT + i] = 0;
        } else {                                    // fp32 tail
            int f = e - CVe;
            float v;
            if (f < 256)        v = ld(preb1, f, f32);
            else if (f < 512)   v = ld(preb2, f - 256, f32);
            else if (f < 1792) {
                int c = f - 512;
                if (c < 256)      v = ld(msgb1, c, f32);
                else if (c < 512) v = 0.f;
                else              v = ld(grubhh, c - 512, f32);
            }
            else if (f < 2560)  v = ld(grubih, f - 1792, f32);
            else if (f < 68096) v = ld(roW1, f - 2560, f32);
            else if (f < 68352) v = ld(rob1, f - 68096, f32);
            else if (f < 72448) v = ld(roW2, f - 68352, f32);
            else                v = ld(rob2, f - 72448, f32);
            w[F_PREB1 + f] = v;
        }
    }

    // Wcomb[k][n] = sum_c W2hat[k][c]*Wih[c][n], k in [0,257) (k=256 -> msg_b2).
    // Slot s: n = s%768, kk = s/768 in [0,86); thread handles k = kk+86j, j<3.
    for (int s = bid * 256 + t; s < 86 * 768; s += 256 * 256) {
        const int n = s % 768, kk = s / 768;
        float acc[3] = {0.f, 0.f, 0.f};
        for (int c = 0; c < 256; ++c) {
            float wv = ld(gruWih, c * 768 + n, f32);   // coalesced, shared over j
#pragma unroll
            for (int j = 0; j < 3; ++j) {
                int k = kk + 86 * j;
                if (k < 257) {
                    float a = (k < 256) ? ld(msgW2, k * 256 + c, f32)
                                        : ld(msgb2, c, f32);
                    acc[j] += a * wv;
                }
            }
        }
#pragma unroll
        for (int j = 0; j < 3; ++j) {
            int k = kk + 86 * j;
            if (k < 257) {
                ushort_t hi = f2b(acc[j]);
                ushort_t lo = f2b(acc[j] - bf2f(hi));
                wb[UB_WCOMBT + n * 896 + k] = hi;
                wb[UB_WCOMBT + n * 896 + 288 + k] = hi;
                wb[UB_WCOMBT + n * 896 + 576 + k] = lo;
            }
        }
    }
}

// bf16 MFMA GEMM: C[M,N] = A[M,K] @ Bt[N,K]^T (+bias)(+relu).
// 128x128 block tile, 4 waves of 64x64, BK=64 with VGPR prefetch.
// C fp32 optional; Cb bf16 optional (stride cbld, lo residual at +cblo).
__global__ __launch_bounds__(256) void mgemm_k(
    const ushort_t* __restrict__ A, const ushort_t* __restrict__ Bt,
    const float* __restrict__ bias, float* __restrict__ C,
    ushort_t* __restrict__ Cb, int cbld, int cblo,
    int K, int N, int dorelu)
{
    __shared__ ushort_t As[128 * LDA];
    __shared__ ushort_t Bs[128 * LDA];
    const int t = threadIdx.x;
    const int wave = t >> 6, lane = t & 63;
    const int ln = lane & 15, quad = lane >> 4;
    const int bm = blockIdx.y * 128, bn = blockIdx.x * 128;
    const int wm = (wave >> 1) * 64, wn = (wave & 1) * 64;
    const int sr = t >> 3;          // 0..31
    const int sc = (t & 7) << 3;    // 0,8,..,56

    f4_t acc[4][4] = {};
    bf8_t ga[4], gb[4];
#pragma unroll
    for (int r = 0; r < 4; ++r) {
        ga[r] = *(const bf8_t*)(&A[(bm + sr + r * 32) * K + sc]);
        gb[r] = *(const bf8_t*)(&Bt[(bn + sr + r * 32) * K + sc]);
    }
    for (int k0 = 0;;) {
        __syncthreads();
#pragma unroll
        for (int r = 0; r < 4; ++r) {
            *(bf8_t*)(&As[(sr + r * 32) * LDA + sc]) = ga[r];
            *(bf8_t*)(&Bs[(sr + r * 32) * LDA + sc]) = gb[r];
        }
        __syncthreads();
        const int kn = k0 + 64;
        if (kn < K) {
#pragma unroll
            for (int r = 0; r < 4; ++r) {
                ga[r] = *(const bf8_t*)(&A[(bm + sr + r * 32) * K + kn + sc]);
                gb[r] = *(const bf8_t*)(&Bt[(bn + sr + r * 32) * K + kn + sc]);
            }
        }
#pragma unroll
        for (int half = 0; half < 2; ++half) {
            bf8_t af[4], bfr[4];
#pragma unroll
            for (int i = 0; i < 4; ++i) {
                af[i]  = *(const bf8_t*)(&As[(wm + i * 16 + ln) * LDA + half * 32 + quad * 8]);
                bfr[i] = *(const bf8_t*)(&Bs[(wn + i * 16 + ln) * LDA + half * 32 + quad * 8]);
            }
#pragma unroll
            for (int mi = 0; mi < 4; ++mi)
#pragma unroll
                for (int ni = 0; ni < 4; ++ni)
                    acc[mi][ni] = __builtin_amdgcn_mfma_f32_16x16x32_bf16(
                        af[mi], bfr[ni], acc[mi][ni], 0, 0, 0);
        }
        k0 = kn;
        if (k0 >= K) break;
    }

#pragma unroll
    for (int mi = 0; mi < 4; ++mi) {
#pragma unroll
        for (int ni = 0; ni < 4; ++ni) {
            int col = bn + wn + ni * 16 + ln;
            float bb = bias ? bias[col] : 0.f;
#pragma unroll
            for (int r = 0; r < 4; ++r) {
                int row = bm + wm + mi * 16 + quad * 4 + r;
                float v = acc[mi][ni][r] + bb;
                if (dorelu) v = relu(v);
                if (C) C[row * N + col] = v;
                if (Cb) {
                    ushort_t hi = f2b(v);
                    Cb[row * cbld + col] = hi;
                    if (cblo) Cb[row * cbld + cblo + col] = f2b(v - bf2f(hi));
                }
            }
        }
    }
}

// msg: 4 rows/block (grid 256); Ehat row = [hi(288)|lo(288)|hi(288)|0(32)].
__global__ __launch_bounds__(256) void msg_kernel(
    const float* __restrict__ hcat,   // [1024][1280]: [hi_p|hj|gh]
    const int*   __restrict__ adj,    // [1024][256]
    ushort_t* __restrict__ ehat)      // [1024][896]
{
    __shared__ float adjf[4 * 256];
    const int t = threadIdx.x;
    const int r0 = blockIdx.x * 4;
#pragma unroll
    for (int rr = 0; rr < 4; ++rr)
        adjf[rr * 256 + t] = (float)adj[(r0 + rr) * 256 + t];
    float hi_[4];
#pragma unroll
    for (int rr = 0; rr < 4; ++rr)
        hi_[rr] = hcat[(r0 + rr) * 1280 + t];
    const float* hjb = hcat + (r0 >> 8) * 256 * 1280 + 256;
    __syncthreads();
    float acc[4] = {0.f, 0.f, 0.f, 0.f};
    float cnt_[4] = {0.f, 0.f, 0.f, 0.f};
#pragma unroll 4
    for (int j = 0; j < 256; ++j) {
        float hjv = hjb[j * 1280 + t];
#pragma unroll
        for (int rr = 0; rr < 4; ++rr) {
            float a = adjf[rr * 256 + j];
            acc[rr] += a * relu(hi_[rr] + hjv);
            cnt_[rr] += a;
        }
    }
#pragma unroll
    for (int rr = 0; rr < 4; ++rr) {
        const int row = r0 + rr;
        ushort_t h16 = f2b(acc[rr]);
        ushort_t l16 = f2b(acc[rr] - bf2f(h16));
        ehat[row * 896 + t] = h16;
        ehat[row * 896 + 288 + t] = l16;
        ehat[row * 896 + 576 + t] = h16;
        if (t < 32) {
            ushort_t d16 = f2b(cnt_[rr]);   // deg <= 256, exact in bf16
            ehat[row * 896 + 256 + t] = (t == 0) ? d16 : 0;
            ehat[row * 896 + 544 + t] = 0;
            ehat[row * 896 + 832 + t] = (t == 0) ? d16 : 0;
            ehat[row * 896 + 864 + t] = 0;
        }
    }
}

// GRU update, 4 rows/block (grid 256).
__global__ __launch_bounds__(256) void gru_kernel(
    const float* __restrict__ gi,     // [1024][768]
    const float* __restrict__ hcat,   // gh at col 512
    float* __restrict__ h,            // fp32 h (in/out)
    ushort_t* __restrict__ h2)        // bf16 hi|lo [1024][512]
{
    const int t = threadIdx.x;
#pragma unroll
    for (int rr = 0; rr < 4; ++rr) {
        const int row = blockIdx.x * 4 + rr;
        const float* gir = gi + row * 768;
        const float* ghr = hcat + row * 1280 + 512;
        float ir = gir[t], iz = gir[256 + t], in = gir[512 + t];
        float hr = ghr[t], hz = ghr[256 + t], hn = ghr[512 + t];
        float r = 1.f / (1.f + __expf(-(ir + hr)));
        float z = 1.f / (1.f + __expf(-(iz + hz)));
        float n = tanhf(in + r * hn);
        float ho = h[row * 256 + t];
        float hv = (1.f - z) * n + z * ho;
        h[row * 256 + t] = hv;
        ushort_t hb = f2b(hv);
        h2[row * 512 + t] = hb;
        h2[row * 512 + 256 + t] = f2b(hv - bf2f(hb));
    }
}

__global__ __launch_bounds__(256) void readout_kernel(
    const float* __restrict__ w_all, void* __restrict__ out)
{
    const float* roW1 = w_all + F_ROW1;
    const float* rob1 = w_all + F_ROB1;
    const float* roW2 = w_all + F_ROW2;
    const float* rob2 = w_all + F_ROB2;
    const int f32 = ((const int*)(w_all + F_FLAG))[0];
    const int b = blockIdx.x;
    const int t = threadIdx.x;
    __shared__ float gl[256], t1[256];
    const float* hb = w_all + F_H + b * 256 * 256;
    float s = 0.f;
    for (int n = 0; n < 256; ++n) s += hb[n * 256 + t];
    gl[t] = s;
    __syncthreads();
    float acc = rob1[t];
    for (int k = 0; k < 256; ++k) acc += gl[k] * roW1[k * 256 + t];
    t1[t] = relu(acc);
    __syncthreads();
    if (t < 16) {
        float q = rob2[t];
        for (int k = 0; k < 256; ++k) q += t1[k] * roW2[k * 16 + t];
        if (f32) ((float*)out)[b * 16 + t] = q;
        else ((__hip_bfloat16*)out)[b * 16 + t] = __float2bfloat16(q);
    }
}

extern "C" void kernel_launch(void* const* d_in, const int* in_sizes, int n_in,
                              void* d_out, int out_size, void* d_ws, size_t ws_size,
                              hipStream_t stream) {
    float* w = (float*)d_ws;
    ushort_t* wb = (ushort_t*)d_ws;

    static const int dictSz[18]  = {65536,262144,16384,256,65536,256,131072,256,65536,256,
                                    196608,196608,768,768,65536,256,4096,16};
    static const int alphaSz[18] = {262144,196608,196608,768,768,131072,65536,256,256,
                                    65536,16384,65536,256,256,65536,4096,256,16};
    static const int alphaPos[18] = {9,0,10,12,11,13,5,7,6,8,2,1,4,3,14,16,15,17};
    bool dictOK = true, alphaOK = true;
    for (int i = 0; i < 18 && i < n_in; ++i) {
        if (in_sizes[i] != dictSz[i])  dictOK = false;
        if (in_sizes[i] != alphaSz[i]) alphaOK = false;
    }
    const void* P[18];
    for (int l = 0; l < 18; ++l) P[l] = d_in[(!dictOK && alphaOK) ? alphaPos[l] : l];
    const int* adj = (const int*)P[1];

    conv_kernel<<<256, 256, 0, stream>>>(
        P[0], P[2], P[3], P[4], P[5], P[6], P[7], P[8], P[9],
        P[10], P[11], P[12], P[13], P[14], P[15], P[16], P[17], w);

    // pre1: X = relu(NF@preW1+b1) -> X2 hi|lo
    mgemm_k<<<dim3(2, 8), 256, 0, stream>>>(
        wb + UB_NFB, wb + UB_PW1T, w + F_PREB1, (float*)0,
        wb + UB_X2, 512, 256, 64, 256, 1);
    // pre2: h = X2@preW2dup + b2 -> F_H fp32 + H2 hi|lo
    mgemm_k<<<dim3(2, 8), 256, 0, stream>>>(
        wb + UB_X2, wb + UB_PW2T, w + F_PREB2, w + F_H,
        wb + UB_H2, 512, 256, 512, 256, 0);

    for (int it = 0; it < 3; ++it) {
        // hcat = h @ [W1_i|W1_j|Whh] + [b1|0|bhh] -> fp32 [1024][1280]
        mgemm_k<<<dim3(10, 8), 256, 0, stream>>>(
            wb + UB_H2, wb + UB_WCATT, w + F_BCAT, w + F_HCAT,
            (ushort_t*)0, 0, 0, 512, 1280, 0);
        msg_kernel<<<256, 256, 0, stream>>>(w + F_HCAT, adj, wb + UB_EHAT);
        // gi = Ehat @ Wcomb + bih (fused agg+gi, K=896) -> fp32 [1024][768]
        mgemm_k<<<dim3(6, 8), 256, 0, stream>>>(
            wb + UB_EHAT, wb + UB_WCOMBT, w + F_BIH, w + F_GI,
            (ushort_t*)0, 0, 0, 896, 768, 0);
        gru_kernel<<<256, 256, 0, stream>>>(w + F_GI, w + F_HCAT,
                                            w + F_H, wb + UB_H2);
    }

    readout_kernel<<<4, 256, 0, stream>>>(w, d_out);
}